// Round 4
// baseline (154.666 us; speedup 1.0000x reference)
//
#include <hip/hip_runtime.h>

#define SS 730
#define GG 4000
#define LENF 15
#define PD 10          // prefetch depth (steps); 730 % 10 == 0
#define TT 10          // route time-tile; 730 % 10 == 0
#define QN ((size_t)SS * GG)

// ---------------------------------------------------------------------------
// Scan kernel: one thread per (cell g, multiplier m); each thread runs BOTH
// the HBV and EXP-HYDRO recurrences for that (g,m). The two independent
// dependent chains interleave in the issue slots (in-thread ILP fills the
// ~4-cyc dependent-latency bubbles that a single chain leaves exposed with
// only 1 wave/SIMD). The forcing prefetch buffer is shared by both models,
// and q_hbv+q_exp is stored as ONE value into slice m (2 slices total).
// ---------------------------------------------------------------------------
template<bool STORE2>
__global__ __launch_bounds__(64) void hydro_scan(const float* __restrict__ x,
                                                 const float* __restrict__ raw,
                                                 float* __restrict__ qsim) {
    int tid = blockIdx.x * 64 + threadIdx.x;
    if (tid >= 2 * GG) return;
    int g = tid % GG;                 // g fast -> coalesced
    int m = tid / GG;
    const float* xg = x + (size_t)g * 3;
    const float* pr = raw + (size_t)g * 38 + m;   // pr[2*i] = raw[g, i*2+m]

    float* qp = qsim + (STORE2 ? (size_t)m * QN : 0) + g;

    // ---- HBV parameters (descale) ----
    float beta  = 1.0f   + pr[0]  * 5.0f;
    float fc    = 50.0f  + pr[2]  * 950.0f;
    float k0    = 0.05f  + pr[4]  * 0.85f;
    float k1    = 0.01f  + pr[6]  * 0.49f;
    float k2    = 0.001f + pr[8]  * 0.199f;
    float lp    = 0.2f   + pr[10] * 0.8f;
    float perc  =          pr[12] * 10.0f;
    float uzl   =          pr[14] * 100.0f;
    float tt    = -2.5f  + pr[16] * 5.0f;
    float cfmax = 0.5f   + pr[18] * 9.5f;
    float cfr   =          pr[20] * 0.1f;
    float cwh   =          pr[22] * 0.2f;
    float invfc   = 1.0f / fc;
    float invlpfc = 1.0f / (lp * fc);
    float cfrcf   = cfr * cfmax;

    // ---- EXP-HYDRO parameters (descale); cols 24 + 2j + m ----
    const float* pe = pr + 24;
    float f    =           pe[0]  * 0.1f;
    float smax = 100.0f  + pe[2]  * 1400.0f;
    float qmax = 10.0f   + pe[4]  * 40.0f;
    float df   =           pe[6]  * 5.0f;
    float tmax =           pe[8]  * 3.0f;
    float tmin = -3.0f   + pe[10] * 3.0f;
    float invsmax = 1.0f / smax;
    float fl = f * 1.44269504f;       // f * log2(e) for exp2f form

    // states
    float sp = 1e-5f, mw = 1e-5f, sm = 0.5f * fc, suz = 1e-5f, slz = 1e-5f;
    float s0 = 1e-5f, s1 = 0.5f * smax;

    // prefetch pipeline: steps 0..PD-1
    float pb[PD], tb[PD], eb[PD];
#pragma unroll
    for (int j = 0; j < PD; ++j) {
        const float* xn = xg + (size_t)j * (3 * GG);
        pb[j] = xn[0]; tb[j] = xn[1]; eb[j] = xn[2];
    }

    auto body = [&](float p, float tc, float pet) -> float {
        // ---- HBV chain ----
        float rain = (tc >= tt) ? p : 0.0f;
        float snow = p - rain;
        sp += snow;
        float melt = fminf(fmaxf(cfmax * (tc - tt), 0.0f), sp);
        mw += melt; sp -= melt;
        float refr = fminf(fmaxf(cfrcf * (tt - tc), 0.0f), mw);
        sp += refr; mw -= refr;
        float tosoil = fmaxf(mw - cwh * sp, 0.0f);
        mw -= tosoil;
        float sw = fminf(exp2f(beta * __log2f(sm * invfc)), 1.0f);
        float rt = rain + tosoil;
        float rech = rt * sw;
        sm += rt - rech;
        float excess = fmaxf(sm - fc, 0.0f);
        sm -= excess;
        float et = fminf(pet * fminf(fmaxf(sm * invlpfc, 0.0f), 1.0f), sm);
        sm = fmaxf(sm - et, 1e-5f);
        suz += rech + excess;
        float pa = fminf(perc, suz);
        suz -= pa;
        float q0 = k0 * fmaxf(suz - uzl, 0.0f);
        suz -= q0;
        float q1 = k1 * suz;
        suz -= q1;
        slz += pa;
        float q2 = k2 * slz;
        slz -= q2;

        // ---- EXP-HYDRO chain (independent; scheduler interleaves) ----
        float ps  = (tc <= tmin) ? p : 0.0f;
        float prr = p - ps;
        float mlt = (tc > tmax) ? fminf(s0, df * (tc - tmax)) : 0.0f;
        s0 += ps - mlt;
        s1 += prr + mlt;
        float qspill = fmaxf(s1 - smax, 0.0f);
        s1 -= qspill;
        float ete = fminf(pet * fminf(fmaxf(s1 * invsmax, 0.0f), 1.0f), s1);
        s1 -= ete;
        float qb = fminf(qmax * exp2f(-fl * fmaxf(smax - s1, 0.0f)), s1);
        s1 -= qb;

        return (q0 + q1 + q2) + (qspill + qb);
    };

    const float* xpre = xg + (size_t)PD * (3 * GG);
    for (int c = 0; c < SS / PD - 1; ++c) {
#pragma unroll
        for (int j = 0; j < PD; ++j) {
            float p = pb[j], tc = tb[j], pet = eb[j];
            pb[j] = xpre[0]; tb[j] = xpre[1]; eb[j] = xpre[2];
            xpre += 3 * GG;
            float q = body(p, tc, pet);
            if (STORE2) *qp = q; else atomicAdd(qp, 0.25f * q);
            qp += GG;
        }
    }
#pragma unroll
    for (int j = 0; j < PD; ++j) {    // peeled last chunk (no prefetch)
        float q = body(pb[j], tb[j], eb[j]);
        if (STORE2) *qp = q; else atomicAdd(qp, 0.25f * q);
        qp += GG;
    }
}

// ---------------------------------------------------------------------------
// Routing kernel, t-tiled: each thread owns one g and TT consecutive t's.
// NB=2: sums the 2 per-m qsim slices inside the window (scale 0.25).
// Gamma-UH weights once per thread; gammaln cancels under normalization:
// w[k] ∝ exp((aa-1)*ln(k+0.5) - (k+0.5)/th).
// ---------------------------------------------------------------------------
template<int NB>
__global__ __launch_bounds__(256) void hydro_route(const float* __restrict__ qsim,
                                                   const float* __restrict__ raw,
                                                   float* __restrict__ out) {
    int idx = blockIdx.x * 256 + threadIdx.x;
    if (idx >= GG * (SS / TT)) return;
    int g = idx % GG;          // g fast -> coalesced
    int c = idx / GG;
    int t0 = c * TT;

    float a = raw[(size_t)g * 38 + 36] * 2.9f;
    float b = raw[(size_t)g * 38 + 37] * 6.5f;
    float aa = fmaxf(a, 0.0f) + 0.1f;
    float th = fmaxf(b, 0.0f) + 0.5f;
    float am1 = aa - 1.0f;
    float invth = 1.0f / th;

    const float logt[LENF] = {
        -0.69314718f, 0.40546511f, 0.91629073f, 1.25276297f, 1.50407740f,
         1.70474809f, 1.87180218f, 2.01490302f, 2.14006616f, 2.25129180f,
         2.35137526f, 2.44234704f, 2.52572864f, 2.60268969f, 2.67414865f };

    float w[LENF];
    float s = 0.0f;
#pragma unroll
    for (int k = 0; k < LENF; ++k) {
        float tk = (float)k + 0.5f;
        w[k] = expf(am1 * logt[k] - tk * invth);
        s += w[k];
    }
    float scale = 0.25f / s;

    // load qsim[t0-14 .. t0+TT-1] (zeros before t=0), summing NB slices
    float v[TT + LENF - 1];
#pragma unroll
    for (int i = 0; i < TT + LENF - 1; ++i) {
        int tp = t0 - (LENF - 1) + i;
        float sv = 0.0f;
        if (tp >= 0) {
            const float* qb = qsim + (size_t)tp * GG + g;
            sv = qb[0];
            if (NB == 2) sv += qb[QN];
        }
        v[i] = sv;
    }
#pragma unroll
    for (int j = 0; j < TT; ++j) {
        float acc = 0.0f;
#pragma unroll
        for (int k = 0; k < LENF; ++k)
            acc += w[k] * v[j + (LENF - 1) - k];
        out[(size_t)(t0 + j) * GG + g] = acc * scale;
    }
}

// ---------------------------------------------------------------------------
extern "C" void kernel_launch(void* const* d_in, const int* in_sizes, int n_in,
                              void* d_out, int out_size, void* d_ws, size_t ws_size,
                              hipStream_t stream) {
    const float* x   = (const float*)d_in[0];   // (730, 4000, 3) f32
    const float* raw = (const float*)d_in[1];   // (4000, 38) f32
    float* out  = (float*)d_out;                // (730, 4000) f32
    float* qsim = (float*)d_ws;

    if (ws_size >= 2 * QN * sizeof(float)) {
        // store path: 2 independent slices (m=0,1), no atomics, no memset
        hydro_scan<true><<<(2 * GG + 63) / 64, 64, 0, stream>>>(x, raw, qsim);
        hydro_route<2><<<(GG * (SS / TT) + 255) / 256, 256, 0, stream>>>(qsim, raw, out);
    } else {
        hipMemsetAsync(qsim, 0, QN * sizeof(float), stream);
        hydro_scan<false><<<(2 * GG + 63) / 64, 64, 0, stream>>>(x, raw, qsim);
        hydro_route<1><<<(GG * (SS / TT) + 255) / 256, 256, 0, stream>>>(qsim, raw, out);
    }
}

// Round 5
// 153.771 us; speedup vs baseline: 1.0058x; 1.0058x over previous
//
#include <hip/hip_runtime.h>

#define SS 730
#define GG 4000
#define LENF 15
#define PD 10          // prefetch depth (steps); 730 % 10 == 0
#define TT 10          // route time-tile; 730 % 10 == 0
#define QN ((size_t)SS * GG)

// ---------------------------------------------------------------------------
// Scan kernel: one thread per (cell g, multiplier m); each thread runs BOTH
// the HBV and EXP-HYDRO recurrences, hand-interleaved so the two independent
// dependent chains fill each other's latency bubbles. __launch_bounds__(64,1)
// (min 1 wave/EU) lifts the 64-VGPR occupancy cap that round-4 showed
// (VGPR=52) -- that cap forced the scheduler to serialize the chains.
// ---------------------------------------------------------------------------
template<bool STORE2>
__global__ __launch_bounds__(64, 1) void hydro_scan(const float* __restrict__ x,
                                                    const float* __restrict__ raw,
                                                    float* __restrict__ qsim) {
    int tid = blockIdx.x * 64 + threadIdx.x;
    if (tid >= 2 * GG) return;
    int g = tid % GG;                 // g fast -> coalesced
    int m = tid / GG;
    const float* xg = x + (size_t)g * 3;
    const float* pr = raw + (size_t)g * 38 + m;   // pr[2*i] = raw[g, i*2+m]

    float* qp = qsim + (STORE2 ? (size_t)m * QN : 0) + g;

    // ---- HBV parameters (descale) ----
    float beta  = 1.0f   + pr[0]  * 5.0f;
    float fc    = 50.0f  + pr[2]  * 950.0f;
    float k0    = 0.05f  + pr[4]  * 0.85f;
    float k1    = 0.01f  + pr[6]  * 0.49f;
    float k2    = 0.001f + pr[8]  * 0.199f;
    float lp    = 0.2f   + pr[10] * 0.8f;
    float perc  =          pr[12] * 10.0f;
    float uzl   =          pr[14] * 100.0f;
    float tt    = -2.5f  + pr[16] * 5.0f;
    float cfmax = 0.5f   + pr[18] * 9.5f;
    float cfr   =          pr[20] * 0.1f;
    float cwh   =          pr[22] * 0.2f;
    float invfc   = 1.0f / fc;
    float invlpfc = 1.0f / (lp * fc);
    float cfrcf   = cfr * cfmax;

    // ---- EXP-HYDRO parameters (descale); cols 24 + 2j + m ----
    const float* pe = pr + 24;
    float f    =           pe[0]  * 0.1f;
    float smax = 100.0f  + pe[2]  * 1400.0f;
    float qmax = 10.0f   + pe[4]  * 40.0f;
    float df   =           pe[6]  * 5.0f;
    float tmax =           pe[8]  * 3.0f;
    float tmin = -3.0f   + pe[10] * 3.0f;
    float invsmax = 1.0f / smax;
    float fl = f * 1.44269504f;       // f * log2(e) for exp2f form

    // states
    float sp = 1e-5f, mw = 1e-5f, sm = 0.5f * fc, suz = 1e-5f, slz = 1e-5f;
    float s0 = 1e-5f, s1 = 0.5f * smax;

    // prefetch pipeline: steps 0..PD-1
    float pb[PD], tb[PD], eb[PD];
#pragma unroll
    for (int j = 0; j < PD; ++j) {
        const float* xn = xg + (size_t)j * (3 * GG);
        pb[j] = xn[0]; tb[j] = xn[1]; eb[j] = xn[2];
    }

    auto body = [&](float p, float tc, float pet) -> float {
        // Long pole first: sw depends only on PREVIOUS-step sm, so its two
        // serial transcendentals overlap the entire rest of the step.
        float sw = fminf(exp2f(beta * __log2f(sm * invfc)), 1.0f);      // H

        // precip partition (both models, independent)
        float rain = (tc >= tt) ? p : 0.0f;                             // H
        float ps   = (tc <= tmin) ? p : 0.0f;                           // E
        float snow = p - rain;                                          // H
        float prr  = p - ps;                                            // E

        // snow-pack chains, interleaved
        sp += snow;                                                     // H
        float mlt = (tc > tmax) ? fminf(s0, df * (tc - tmax)) : 0.0f;   // E
        float melt = fminf(fmaxf(cfmax * (tc - tt), 0.0f), sp);         // H
        s0 += ps - mlt;                                                 // E
        mw += melt; sp -= melt;                                         // H
        s1 += prr + mlt;                                                // E
        float refr = fminf(fmaxf(cfrcf * (tt - tc), 0.0f), mw);         // H
        float qspill = fmaxf(s1 - smax, 0.0f);                          // E
        sp += refr; mw -= refr;                                         // H
        s1 -= qspill;                                                   // E
        float tosoil = fmaxf(mw - cwh * sp, 0.0f);                      // H
        float ete = fminf(pet * fminf(fmaxf(s1 * invsmax, 0.0f), 1.0f), s1); // E
        mw -= tosoil;                                                   // H
        s1 -= ete;                                                      // E

        // soil chain (H) vs baseflow exp chain (E)
        float rt = rain + tosoil;                                       // H
        float qb = fminf(qmax * exp2f(-fl * fmaxf(smax - s1, 0.0f)), s1); // E
        float rech = rt * sw;                                           // H
        sm += rt - rech;                                                // H
        s1 -= qb;                                                       // E
        float excess = fmaxf(sm - fc, 0.0f);                            // H
        sm -= excess;                                                   // H
        float et = fminf(pet * fminf(fmaxf(sm * invlpfc, 0.0f), 1.0f), sm); // H
        sm = fmaxf(sm - et, 1e-5f);                                     // H

        // routing stores (H)
        suz += rech + excess;
        float pa = fminf(perc, suz);
        suz -= pa;
        float q0 = k0 * fmaxf(suz - uzl, 0.0f);
        suz -= q0;
        float q1 = k1 * suz;
        suz -= q1;
        slz += pa;
        float q2 = k2 * slz;
        slz -= q2;

        return (q0 + q1 + q2) + (qspill + qb);
    };

    const float* xpre = xg + (size_t)PD * (3 * GG);
    for (int c = 0; c < SS / PD - 1; ++c) {
#pragma unroll
        for (int j = 0; j < PD; ++j) {
            float p = pb[j], tc = tb[j], pet = eb[j];
            pb[j] = xpre[0]; tb[j] = xpre[1]; eb[j] = xpre[2];
            xpre += 3 * GG;
            float q = body(p, tc, pet);
            if (STORE2) *qp = q; else atomicAdd(qp, 0.25f * q);
            qp += GG;
        }
    }
#pragma unroll
    for (int j = 0; j < PD; ++j) {    // peeled last chunk (no prefetch)
        float q = body(pb[j], tb[j], eb[j]);
        if (STORE2) *qp = q; else atomicAdd(qp, 0.25f * q);
        qp += GG;
    }
}

// ---------------------------------------------------------------------------
// Routing kernel, t-tiled: each thread owns one g and TT consecutive t's.
// NB=2: sums the 2 per-m qsim slices inside the window (scale 0.25).
// Gamma-UH weights once per thread; gammaln cancels under normalization:
// w[k] ∝ exp((aa-1)*ln(k+0.5) - (k+0.5)/th).
// ---------------------------------------------------------------------------
template<int NB>
__global__ __launch_bounds__(256) void hydro_route(const float* __restrict__ qsim,
                                                   const float* __restrict__ raw,
                                                   float* __restrict__ out) {
    int idx = blockIdx.x * 256 + threadIdx.x;
    if (idx >= GG * (SS / TT)) return;
    int g = idx % GG;          // g fast -> coalesced
    int c = idx / GG;
    int t0 = c * TT;

    float a = raw[(size_t)g * 38 + 36] * 2.9f;
    float b = raw[(size_t)g * 38 + 37] * 6.5f;
    float aa = fmaxf(a, 0.0f) + 0.1f;
    float th = fmaxf(b, 0.0f) + 0.5f;
    float am1 = aa - 1.0f;
    float invth = 1.0f / th;

    const float logt[LENF] = {
        -0.69314718f, 0.40546511f, 0.91629073f, 1.25276297f, 1.50407740f,
         1.70474809f, 1.87180218f, 2.01490302f, 2.14006616f, 2.25129180f,
         2.35137526f, 2.44234704f, 2.52572864f, 2.60268969f, 2.67414865f };

    float w[LENF];
    float s = 0.0f;
#pragma unroll
    for (int k = 0; k < LENF; ++k) {
        float tk = (float)k + 0.5f;
        w[k] = expf(am1 * logt[k] - tk * invth);
        s += w[k];
    }
    float scale = 0.25f / s;

    // load qsim[t0-14 .. t0+TT-1] (zeros before t=0), summing NB slices
    float v[TT + LENF - 1];
#pragma unroll
    for (int i = 0; i < TT + LENF - 1; ++i) {
        int tp = t0 - (LENF - 1) + i;
        float sv = 0.0f;
        if (tp >= 0) {
            const float* qb = qsim + (size_t)tp * GG + g;
            sv = qb[0];
            if (NB == 2) sv += qb[QN];
        }
        v[i] = sv;
    }
#pragma unroll
    for (int j = 0; j < TT; ++j) {
        float acc = 0.0f;
#pragma unroll
        for (int k = 0; k < LENF; ++k)
            acc += w[k] * v[j + (LENF - 1) - k];
        out[(size_t)(t0 + j) * GG + g] = acc * scale;
    }
}

// ---------------------------------------------------------------------------
extern "C" void kernel_launch(void* const* d_in, const int* in_sizes, int n_in,
                              void* d_out, int out_size, void* d_ws, size_t ws_size,
                              hipStream_t stream) {
    const float* x   = (const float*)d_in[0];   // (730, 4000, 3) f32
    const float* raw = (const float*)d_in[1];   // (4000, 38) f32
    float* out  = (float*)d_out;                // (730, 4000) f32
    float* qsim = (float*)d_ws;

    if (ws_size >= 2 * QN * sizeof(float)) {
        // store path: 2 independent slices (m=0,1), no atomics, no memset
        hydro_scan<true><<<(2 * GG + 63) / 64, 64, 0, stream>>>(x, raw, qsim);
        hydro_route<2><<<(GG * (SS / TT) + 255) / 256, 256, 0, stream>>>(qsim, raw, out);
    } else {
        hipMemsetAsync(qsim, 0, QN * sizeof(float), stream);
        hydro_scan<false><<<(2 * GG + 63) / 64, 64, 0, stream>>>(x, raw, qsim);
        hydro_route<1><<<(GG * (SS / TT) + 255) / 256, 256, 0, stream>>>(qsim, raw, out);
    }
}

// Round 6
// 115.180 us; speedup vs baseline: 1.3428x; 1.3351x over previous
//
#include <hip/hip_runtime.h>

#define SS 730
#define GG 4000
#define LENF 15
#define PD 10          // prefetch depth (steps); 730 % 10 == 0
#define GPAD 4032      // 63 waves per instance -> no wave mixes models
#define TT 10          // route time-tile; 730 % 10 == 0
#define QN ((size_t)SS * GG)

// ---------------------------------------------------------------------------
// Scan kernel: one thread per (cell g, multiplier m, model) -- SPLIT topology
// (round-3 revert: with ~1000 idle SIMDs, HBV and EXP in separate waves run
// fully in parallel; fusing them in one thread serializes partially and
// loses). inst = tid/GPAD: 0,1 -> HBV (m=inst&1); 2,3 -> EXP (m=inst&1).
// Dependent-chain trims (all provable no-ops algebraically):
//   * sm <= fc invariant  -> (sm/fc)^beta <= 1, drop the min(,1)
//   * sm > 0              -> drop max(,0) in ET clip
//   * s1 in [0,smax]      -> drop both clips in EXP ET and max(smax-s1,0)
//   * exp(-f*x) = exp2(-f*log2e*x), transcendental pair hoisted to step top
// ---------------------------------------------------------------------------
template<bool STORE4>
__global__ __launch_bounds__(64, 1) void hydro_scan(const float* __restrict__ x,
                                                    const float* __restrict__ raw,
                                                    float* __restrict__ qsim) {
    int tid = blockIdx.x * 64 + threadIdx.x;
    int g = tid % GPAD;
    int inst = tid / GPAD;
    if (g >= GG) return;
    int m = inst & 1;
    const float* xg = x + (size_t)g * 3;
    const float* pr = raw + (size_t)g * 38 + m;   // pr[2*i] = raw[g, i*2+m]

    float* qp = qsim + (STORE4 ? (size_t)inst * QN : 0) + g;

    // prefetch pipeline: steps 0..PD-1
    float pb[PD], tb[PD], eb[PD];
#pragma unroll
    for (int j = 0; j < PD; ++j) {
        const float* xn = xg + (size_t)j * (3 * GG);
        pb[j] = xn[0]; tb[j] = xn[1]; eb[j] = xn[2];
    }

    if (inst < 2) {
        // ---- HBV parameters (descale) ----
        float beta  = 1.0f   + pr[0]  * 5.0f;
        float fc    = 50.0f  + pr[2]  * 950.0f;
        float k0    = 0.05f  + pr[4]  * 0.85f;
        float k1    = 0.01f  + pr[6]  * 0.49f;
        float k2    = 0.001f + pr[8]  * 0.199f;
        float lp    = 0.2f   + pr[10] * 0.8f;
        float perc  =          pr[12] * 10.0f;
        float uzl   =          pr[14] * 100.0f;
        float tt    = -2.5f  + pr[16] * 5.0f;
        float cfmax = 0.5f   + pr[18] * 9.5f;
        float cfr   =          pr[20] * 0.1f;
        float cwh   =          pr[22] * 0.2f;
        float invfc   = 1.0f / fc;
        float invlpfc = 1.0f / (lp * fc);
        float cfrcf   = cfr * cfmax;

        float sp = 1e-5f, mw = 1e-5f, sm = 0.5f * fc, suz = 1e-5f, slz = 1e-5f;

        auto body = [&](float p, float tc, float pet) -> float {
            // long pole first: depends only on PREVIOUS-step sm
            float sw = exp2f(beta * __log2f(sm * invfc));   // <=1 by invariant
            float rain = (tc >= tt) ? p : 0.0f;
            float snow = p - rain;
            sp += snow;
            float melt = fminf(fmaxf(cfmax * (tc - tt), 0.0f), sp);
            mw += melt; sp -= melt;
            float refr = fminf(fmaxf(cfrcf * (tt - tc), 0.0f), mw);
            sp += refr; mw -= refr;
            float tosoil = fmaxf(mw - cwh * sp, 0.0f);
            mw -= tosoil;
            float rt = rain + tosoil;
            float rech = rt * sw;
            sm += rt - rech;
            float excess = fmaxf(sm - fc, 0.0f);
            sm -= excess;
            float et = fminf(pet * fminf(sm * invlpfc, 1.0f), sm);
            sm = fmaxf(sm - et, 1e-5f);
            suz += rech + excess;
            float pa = fminf(perc, suz);
            suz -= pa;
            float q0 = k0 * fmaxf(suz - uzl, 0.0f);
            suz -= q0;
            float q1 = k1 * suz;
            suz -= q1;
            slz += pa;
            float q2 = k2 * slz;
            slz -= q2;
            return q0 + q1 + q2;
        };

        const float* xpre = xg + (size_t)PD * (3 * GG);
        for (int c = 0; c < SS / PD - 1; ++c) {
#pragma unroll
            for (int j = 0; j < PD; ++j) {
                float p = pb[j], tc = tb[j], pet = eb[j];
                pb[j] = xpre[0]; tb[j] = xpre[1]; eb[j] = xpre[2];
                xpre += 3 * GG;
                float q = body(p, tc, pet);
                if (STORE4) *qp = q; else atomicAdd(qp, 0.25f * q);
                qp += GG;
            }
        }
#pragma unroll
        for (int j = 0; j < PD; ++j) {           // peeled last chunk
            float q = body(pb[j], tb[j], eb[j]);
            if (STORE4) *qp = q; else atomicAdd(qp, 0.25f * q);
            qp += GG;
        }
    } else {
        // ---- EXP-HYDRO parameters (descale); cols 24 + 2j + m ----
        const float* pe = pr + 24;
        float f    =           pe[0]  * 0.1f;
        float smax = 100.0f  + pe[2]  * 1400.0f;
        float qmax = 10.0f   + pe[4]  * 40.0f;
        float df   =           pe[6]  * 5.0f;
        float tmax =           pe[8]  * 3.0f;
        float tmin = -3.0f   + pe[10] * 3.0f;
        float invsmax = 1.0f / smax;
        float fl = f * 1.44269504f;              // f * log2(e)

        float s0 = 1e-5f, s1 = 0.5f * smax;

        auto body = [&](float p, float tc, float pet) -> float {
            float ps  = (tc <= tmin) ? p : 0.0f;
            float prr = p - ps;
            float mlt = (tc > tmax) ? fminf(s0, df * (tc - tmax)) : 0.0f;
            s0 += ps - mlt;
            s1 += prr + mlt;
            float qspill = fmaxf(s1 - smax, 0.0f);
            s1 -= qspill;                                    // s1 in [0,smax]
            float et = fminf(pet * (s1 * invsmax), s1);
            s1 -= et;
            float qb = fminf(qmax * exp2f(-fl * (smax - s1)), s1);
            s1 -= qb;
            return qspill + qb;
        };

        const float* xpre = xg + (size_t)PD * (3 * GG);
        for (int c = 0; c < SS / PD - 1; ++c) {
#pragma unroll
            for (int j = 0; j < PD; ++j) {
                float p = pb[j], tc = tb[j], pet = eb[j];
                pb[j] = xpre[0]; tb[j] = xpre[1]; eb[j] = xpre[2];
                xpre += 3 * GG;
                float q = body(p, tc, pet);
                if (STORE4) *qp = q; else atomicAdd(qp, 0.25f * q);
                qp += GG;
            }
        }
#pragma unroll
        for (int j = 0; j < PD; ++j) {
            float q = body(pb[j], tb[j], eb[j]);
            if (STORE4) *qp = q; else atomicAdd(qp, 0.25f * q);
            qp += GG;
        }
    }
}

// ---------------------------------------------------------------------------
// UH weights: one thread per g, computes the 15 normalized gamma-UH weights
// once (with the 0.25 instance-average folded in) into wbuf[k*GG+g].
// gammaln cancels under normalization: w[k] ∝ exp((aa-1)ln(k+.5)-(k+.5)/th).
// ---------------------------------------------------------------------------
__global__ __launch_bounds__(256) void uh_weights(const float* __restrict__ raw,
                                                  float* __restrict__ wbuf) {
    int g = blockIdx.x * 256 + threadIdx.x;
    if (g >= GG) return;
    float a = raw[(size_t)g * 38 + 36] * 2.9f;
    float b = raw[(size_t)g * 38 + 37] * 6.5f;
    float aa = fmaxf(a, 0.0f) + 0.1f;
    float th = fmaxf(b, 0.0f) + 0.5f;
    float am1 = aa - 1.0f;
    float invth = 1.0f / th;

    const float logt[LENF] = {
        -0.69314718f, 0.40546511f, 0.91629073f, 1.25276297f, 1.50407740f,
         1.70474809f, 1.87180218f, 2.01490302f, 2.14006616f, 2.25129180f,
         2.35137526f, 2.44234704f, 2.52572864f, 2.60268969f, 2.67414865f };

    float w[LENF];
    float s = 0.0f;
#pragma unroll
    for (int k = 0; k < LENF; ++k) {
        float tk = (float)k + 0.5f;
        w[k] = expf(am1 * logt[k] - tk * invth);
        s += w[k];
    }
    float scale = 0.25f / s;
#pragma unroll
    for (int k = 0; k < LENF; ++k)
        wbuf[(size_t)k * GG + g] = w[k] * scale;
}

// ---------------------------------------------------------------------------
// Routing kernel, t-tiled: each thread owns one g and TT consecutive t's.
// WPRE: weights preloaded from wbuf (scale folded). NB = #qsim slices summed.
// ---------------------------------------------------------------------------
template<int NB, bool WPRE>
__global__ __launch_bounds__(256) void hydro_route(const float* __restrict__ qsim,
                                                   const float* __restrict__ raw,
                                                   const float* __restrict__ wbuf,
                                                   float* __restrict__ out) {
    int idx = blockIdx.x * 256 + threadIdx.x;
    if (idx >= GG * (SS / TT)) return;
    int g = idx % GG;          // g fast -> coalesced
    int c = idx / GG;
    int t0 = c * TT;

    float w[LENF];
    float scale;
    if (WPRE) {
#pragma unroll
        for (int k = 0; k < LENF; ++k)
            w[k] = wbuf[(size_t)k * GG + g];
        scale = 1.0f;
    } else {
        float a = raw[(size_t)g * 38 + 36] * 2.9f;
        float b = raw[(size_t)g * 38 + 37] * 6.5f;
        float aa = fmaxf(a, 0.0f) + 0.1f;
        float th = fmaxf(b, 0.0f) + 0.5f;
        float am1 = aa - 1.0f;
        float invth = 1.0f / th;
        const float logt[LENF] = {
            -0.69314718f, 0.40546511f, 0.91629073f, 1.25276297f, 1.50407740f,
             1.70474809f, 1.87180218f, 2.01490302f, 2.14006616f, 2.25129180f,
             2.35137526f, 2.44234704f, 2.52572864f, 2.60268969f, 2.67414865f };
        float s = 0.0f;
#pragma unroll
        for (int k = 0; k < LENF; ++k) {
            float tk = (float)k + 0.5f;
            w[k] = expf(am1 * logt[k] - tk * invth);
            s += w[k];
        }
        // NB==4: raw q stored -> fold 0.25; NB==1: atomics already 0.25-scaled
        scale = (NB == 4 ? 0.25f : 1.0f) / s;
    }

    // load qsim[t0-14 .. t0+TT-1] (zeros before t=0), summing NB slices
    float v[TT + LENF - 1];
#pragma unroll
    for (int i = 0; i < TT + LENF - 1; ++i) {
        int tp = t0 - (LENF - 1) + i;
        float sv = 0.0f;
        if (tp >= 0) {
            const float* qb = qsim + (size_t)tp * GG + g;
            sv = qb[0];
            if (NB == 4) sv += qb[QN] + qb[2 * QN] + qb[3 * QN];
        }
        v[i] = sv;
    }
#pragma unroll
    for (int j = 0; j < TT; ++j) {
        float acc = 0.0f;
#pragma unroll
        for (int k = 0; k < LENF; ++k)
            acc += w[k] * v[j + (LENF - 1) - k];
        out[(size_t)(t0 + j) * GG + g] = (WPRE ? acc : acc * scale);
    }
}

// ---------------------------------------------------------------------------
extern "C" void kernel_launch(void* const* d_in, const int* in_sizes, int n_in,
                              void* d_out, int out_size, void* d_ws, size_t ws_size,
                              hipStream_t stream) {
    const float* x   = (const float*)d_in[0];   // (730, 4000, 3) f32
    const float* raw = (const float*)d_in[1];   // (4000, 38) f32
    float* out  = (float*)d_out;                // (730, 4000) f32
    float* qsim = (float*)d_ws;

    const size_t slices4 = 4 * QN * sizeof(float);
    const size_t wbytes  = (size_t)LENF * GG * sizeof(float);
    int rblocks = (GG * (SS / TT) + 255) / 256;

    if (ws_size >= slices4 + wbytes) {
        float* wbuf = qsim + 4 * QN;
        hydro_scan<true><<<(4 * GPAD) / 64, 64, 0, stream>>>(x, raw, qsim);
        uh_weights<<<(GG + 255) / 256, 256, 0, stream>>>(raw, wbuf);
        hydro_route<4, true><<<rblocks, 256, 0, stream>>>(qsim, raw, wbuf, out);
    } else if (ws_size >= slices4) {
        hydro_scan<true><<<(4 * GPAD) / 64, 64, 0, stream>>>(x, raw, qsim);
        hydro_route<4, false><<<rblocks, 256, 0, stream>>>(qsim, raw, nullptr, out);
    } else {
        hipMemsetAsync(qsim, 0, QN * sizeof(float), stream);
        hydro_scan<false><<<(4 * GPAD) / 64, 64, 0, stream>>>(x, raw, qsim);
        hydro_route<1, false><<<rblocks, 256, 0, stream>>>(qsim, raw, nullptr, out);
    }
}

// Round 7
// 111.204 us; speedup vs baseline: 1.3908x; 1.0358x over previous
//
#include <hip/hip_runtime.h>

#define SS 730
#define GG 4000
#define LENF 15
#define PD 10          // prefetch depth (steps); 730 % 10 == 0
#define GPAD 4032      // 63 waves per instance -> no wave mixes models
#define TT 10          // route time-tile; 730 % 10 == 0
#define QN ((size_t)SS * GG)
#define QNI ((int)(SS * GG))

// ---------------------------------------------------------------------------
// Scan kernel: one thread per (cell g, multiplier m, model), SPLIT topology.
// inst = tid/GPAD: 0,1 -> HBV (m=inst&1); 2,3 -> EXP (m=inst&1).
// Round-7 restructuring: algebraically-exact rewrites that (a) move clip
// bounds that depend only on forcing OFF the dependent chain, (b) collapse
// sub+max / min+sub pairs, (c) use max3 for the ET update, (d) fold qmax
// into the exp2 argument, (e) 32-bit offset addressing.
// ---------------------------------------------------------------------------
template<bool STORE4>
__global__ __launch_bounds__(64, 1) void hydro_scan(const float* __restrict__ x,
                                                    const float* __restrict__ raw,
                                                    float* __restrict__ qsim) {
    int tid = blockIdx.x * 64 + threadIdx.x;
    int g = tid % GPAD;
    int inst = tid / GPAD;
    if (g >= GG) return;
    int m = inst & 1;
    const float* pr = raw + (size_t)g * 38 + m;   // pr[2*i] = raw[g, i*2+m]

    int xoff = g * 3;
    int qoff = g + (STORE4 ? inst * QNI : 0);

    // prefetch pipeline: steps 0..PD-1
    float pb[PD], tb[PD], eb[PD];
#pragma unroll
    for (int j = 0; j < PD; ++j) {
        pb[j] = x[xoff]; tb[j] = x[xoff + 1]; eb[j] = x[xoff + 2];
        xoff += 3 * GG;
    }

    if (inst < 2) {
        // ---- HBV parameters (descale + derived constants) ----
        float beta  = 1.0f   + pr[0]  * 5.0f;
        float fc    = 50.0f  + pr[2]  * 950.0f;
        float k0    = 0.05f  + pr[4]  * 0.85f;
        float k1    = 0.01f  + pr[6]  * 0.49f;
        float k2    = 0.001f + pr[8]  * 0.199f;
        float lp    = 0.2f   + pr[10] * 0.8f;
        float perc  =          pr[12] * 10.0f;
        float uzl   =          pr[14] * 100.0f;
        float tt    = -2.5f  + pr[16] * 5.0f;
        float cfmax = 0.5f   + pr[18] * 9.5f;
        float cfr   =          pr[20] * 0.1f;
        float cwh   =          pr[22] * 0.2f;
        float invfc   = 1.0f / fc;
        float invlpfc = 1.0f / (lp * fc);
        float ncfrcf  = -(cfr * cfmax);
        float omk0    = 1.0f - k0;
        float k0uzl   = k0 * uzl;
        float omk1    = 1.0f - k1;

        float sp = 1e-5f, mw = 1e-5f, sm = 0.5f * fc, suz = 1e-5f, slz = 1e-5f;

        auto body = [&](float p, float tc, float pet) -> float {
            // off-chain (forcing-only) terms
            float dt   = tc - tt;
            float msn  = fmaxf(cfmax * dt, 0.0f);
            float mrf  = fmaxf(ncfrcf * dt, 0.0f);
            float rain = (dt >= 0.0f) ? p : 0.0f;
            float snow = p - rain;
            float etk  = fmaf(-invlpfc, pet, 1.0f);      // 1 - pet/(lp*fc)
            // sw from PREVIOUS-step sm (long pole first)
            float sw   = exp2f(beta * __log2f(sm * invfc));   // <= 1 (sm<=fc)
            float omsw = 1.0f - sw;
            // snow / melt-water chains
            float sp1  = sp + snow;
            float melt = fminf(msn, sp1);
            float mw2  = mw + melt;
            float sp2  = sp1 - melt;
            float refr = fminf(mrf, mw2);
            float mw3  = mw2 - refr;
            sp = sp2 + refr;
            float mw4  = fminf(mw3, cwh * sp);
            float tosoil = mw3 - mw4;
            mw = mw4;
            // soil moisture
            float rt    = rain + tosoil;
            float sm1   = fmaf(rt, omsw, sm);            // sm + rt - rech
            float rech  = rt * sw;
            float excess = fmaxf(sm1 - fc, 0.0f);
            float sm2   = fminf(sm1, fc);
            sm = fmaxf(fmaxf(sm2 * etk, sm2 - pet), 1e-5f);   // v_max3
            // upper / lower zones
            float suz1 = suz + rech + excess;
            float suz2 = fmaxf(suz1 - perc, 0.0f);
            float pa   = suz1 - suz2;                    // = min(perc, suz1)
            float suz3 = fminf(suz2, fmaf(suz2, omk0, k0uzl));
            float suzn = omk1 * suz3;
            float q01  = suz2 - suzn;                    // q0 + q1
            suz = suzn;
            float slz1 = slz + pa;
            float q2   = k2 * slz1;
            slz = slz1 - q2;
            return q01 + q2;
        };

        for (int c = 0; c < SS / PD - 1; ++c) {
#pragma unroll
            for (int j = 0; j < PD; ++j) {
                float p = pb[j], tc = tb[j], pet = eb[j];
                pb[j] = x[xoff]; tb[j] = x[xoff + 1]; eb[j] = x[xoff + 2];
                xoff += 3 * GG;
                float q = body(p, tc, pet);
                if (STORE4) qsim[qoff] = q; else atomicAdd(&qsim[qoff], 0.25f * q);
                qoff += GG;
            }
        }
#pragma unroll
        for (int j = 0; j < PD; ++j) {           // peeled last chunk
            float q = body(pb[j], tb[j], eb[j]);
            if (STORE4) qsim[qoff] = q; else atomicAdd(&qsim[qoff], 0.25f * q);
            qoff += GG;
        }
    } else {
        // ---- EXP-HYDRO parameters (descale + derived constants) ----
        const float* pe = pr + 24;
        float f    =           pe[0]  * 0.1f;
        float smax = 100.0f  + pe[2]  * 1400.0f;
        float qmax = 10.0f   + pe[4]  * 40.0f;
        float df   =           pe[6]  * 5.0f;
        float tmax =           pe[8]  * 3.0f;
        float tmin = -3.0f   + pe[10] * 3.0f;
        float invsmax = 1.0f / smax;
        float fl = f * 1.44269504f;              // f * log2(e)
        float c0 = __log2f(qmax) - fl * smax;    // fold qmax into exponent

        float s0 = 1e-5f, s1 = 0.5f * smax;

        auto body = [&](float p, float tc, float pet) -> float {
            // off-chain terms
            float mdf = df * fmaxf(tc - tmax, 0.0f);
            float ps  = (tc <= tmin) ? p : 0.0f;
            float prr = p - ps;
            float etk = fmaxf(fmaf(-invsmax, pet, 1.0f), 0.0f);
            // chains
            float mlt = fminf(s0, mdf);
            s0 = fmaxf(s0 - mdf, 0.0f) + ps;
            float s1a = s1 + prr + mlt;
            float qspill = fmaxf(s1a - smax, 0.0f);
            float s1b = fminf(s1a, smax);
            float s1c = s1b * etk;                       // s1b - et (exact)
            float qb  = fminf(exp2f(fmaf(fl, s1c, c0)), s1c);
            s1 = s1c - qb;
            return qspill + qb;
        };

        for (int c = 0; c < SS / PD - 1; ++c) {
#pragma unroll
            for (int j = 0; j < PD; ++j) {
                float p = pb[j], tc = tb[j], pet = eb[j];
                pb[j] = x[xoff]; tb[j] = x[xoff + 1]; eb[j] = x[xoff + 2];
                xoff += 3 * GG;
                float q = body(p, tc, pet);
                if (STORE4) qsim[qoff] = q; else atomicAdd(&qsim[qoff], 0.25f * q);
                qoff += GG;
            }
        }
#pragma unroll
        for (int j = 0; j < PD; ++j) {
            float q = body(pb[j], tb[j], eb[j]);
            if (STORE4) qsim[qoff] = q; else atomicAdd(&qsim[qoff], 0.25f * q);
            qoff += GG;
        }
    }
}

// ---------------------------------------------------------------------------
// UH weights: one thread per g, computes the 15 normalized gamma-UH weights
// once (0.25 instance-average folded in) into wbuf[k*GG+g]. gammaln cancels
// under normalization: w[k] ∝ exp((aa-1)ln(k+.5)-(k+.5)/th).
// ---------------------------------------------------------------------------
__global__ __launch_bounds__(256) void uh_weights(const float* __restrict__ raw,
                                                  float* __restrict__ wbuf) {
    int g = blockIdx.x * 256 + threadIdx.x;
    if (g >= GG) return;
    float a = raw[(size_t)g * 38 + 36] * 2.9f;
    float b = raw[(size_t)g * 38 + 37] * 6.5f;
    float aa = fmaxf(a, 0.0f) + 0.1f;
    float th = fmaxf(b, 0.0f) + 0.5f;
    float am1 = aa - 1.0f;
    float invth = 1.0f / th;

    const float logt[LENF] = {
        -0.69314718f, 0.40546511f, 0.91629073f, 1.25276297f, 1.50407740f,
         1.70474809f, 1.87180218f, 2.01490302f, 2.14006616f, 2.25129180f,
         2.35137526f, 2.44234704f, 2.52572864f, 2.60268969f, 2.67414865f };

    float w[LENF];
    float s = 0.0f;
#pragma unroll
    for (int k = 0; k < LENF; ++k) {
        float tk = (float)k + 0.5f;
        w[k] = expf(am1 * logt[k] - tk * invth);
        s += w[k];
    }
    float scale = 0.25f / s;
#pragma unroll
    for (int k = 0; k < LENF; ++k)
        wbuf[(size_t)k * GG + g] = w[k] * scale;
}

// ---------------------------------------------------------------------------
// Routing kernel, t-tiled: each thread owns one g and TT consecutive t's.
// WPRE: weights preloaded from wbuf (scale folded). NB = #qsim slices summed.
// ---------------------------------------------------------------------------
template<int NB, bool WPRE>
__global__ __launch_bounds__(256) void hydro_route(const float* __restrict__ qsim,
                                                   const float* __restrict__ raw,
                                                   const float* __restrict__ wbuf,
                                                   float* __restrict__ out) {
    int idx = blockIdx.x * 256 + threadIdx.x;
    if (idx >= GG * (SS / TT)) return;
    int g = idx % GG;          // g fast -> coalesced
    int c = idx / GG;
    int t0 = c * TT;

    float w[LENF];
    float scale;
    if (WPRE) {
#pragma unroll
        for (int k = 0; k < LENF; ++k)
            w[k] = wbuf[(size_t)k * GG + g];
        scale = 1.0f;
    } else {
        float a = raw[(size_t)g * 38 + 36] * 2.9f;
        float b = raw[(size_t)g * 38 + 37] * 6.5f;
        float aa = fmaxf(a, 0.0f) + 0.1f;
        float th = fmaxf(b, 0.0f) + 0.5f;
        float am1 = aa - 1.0f;
        float invth = 1.0f / th;
        const float logt[LENF] = {
            -0.69314718f, 0.40546511f, 0.91629073f, 1.25276297f, 1.50407740f,
             1.70474809f, 1.87180218f, 2.01490302f, 2.14006616f, 2.25129180f,
             2.35137526f, 2.44234704f, 2.52572864f, 2.60268969f, 2.67414865f };
        float s = 0.0f;
#pragma unroll
        for (int k = 0; k < LENF; ++k) {
            float tk = (float)k + 0.5f;
            w[k] = expf(am1 * logt[k] - tk * invth);
            s += w[k];
        }
        scale = (NB == 4 ? 0.25f : 1.0f) / s;
    }

    // load qsim[t0-14 .. t0+TT-1] (zeros before t=0), summing NB slices
    float v[TT + LENF - 1];
#pragma unroll
    for (int i = 0; i < TT + LENF - 1; ++i) {
        int tp = t0 - (LENF - 1) + i;
        float sv = 0.0f;
        if (tp >= 0) {
            const float* qb = qsim + (size_t)tp * GG + g;
            sv = qb[0];
            if (NB == 4) sv += qb[QN] + qb[2 * QN] + qb[3 * QN];
        }
        v[i] = sv;
    }
#pragma unroll
    for (int j = 0; j < TT; ++j) {
        float acc = 0.0f;
#pragma unroll
        for (int k = 0; k < LENF; ++k)
            acc += w[k] * v[j + (LENF - 1) - k];
        out[(size_t)(t0 + j) * GG + g] = (WPRE ? acc : acc * scale);
    }
}

// ---------------------------------------------------------------------------
extern "C" void kernel_launch(void* const* d_in, const int* in_sizes, int n_in,
                              void* d_out, int out_size, void* d_ws, size_t ws_size,
                              hipStream_t stream) {
    const float* x   = (const float*)d_in[0];   // (730, 4000, 3) f32
    const float* raw = (const float*)d_in[1];   // (4000, 38) f32
    float* out  = (float*)d_out;                // (730, 4000) f32
    float* qsim = (float*)d_ws;

    const size_t slices4 = 4 * QN * sizeof(float);
    const size_t wbytes  = (size_t)LENF * GG * sizeof(float);
    int rblocks = (GG * (SS / TT) + 255) / 256;

    if (ws_size >= slices4 + wbytes) {
        float* wbuf = qsim + 4 * QN;
        hydro_scan<true><<<(4 * GPAD) / 64, 64, 0, stream>>>(x, raw, qsim);
        uh_weights<<<(GG + 255) / 256, 256, 0, stream>>>(raw, wbuf);
        hydro_route<4, true><<<rblocks, 256, 0, stream>>>(qsim, raw, wbuf, out);
    } else if (ws_size >= slices4) {
        hydro_scan<true><<<(4 * GPAD) / 64, 64, 0, stream>>>(x, raw, qsim);
        hydro_route<4, false><<<rblocks, 256, 0, stream>>>(qsim, raw, nullptr, out);
    } else {
        hipMemsetAsync(qsim, 0, QN * sizeof(float), stream);
        hydro_scan<false><<<(4 * GPAD) / 64, 64, 0, stream>>>(x, raw, qsim);
        hydro_route<1, false><<<rblocks, 256, 0, stream>>>(qsim, raw, nullptr, out);
    }
}